// Round 4
// baseline (6525.407 us; speedup 1.0000x reference)
//
#include <hip/hip_runtime.h>
#include <hip/hip_bf16.h>
#include <cstdint>
#include <cstddef>

// Problem dims (fixed by reference)
#define BB    8
#define TT    1024
#define DD    1024
#define NHEAD 16
#define HDIM  64
#define FF    4096

typedef unsigned short u16;
typedef unsigned int   u32;

__device__ __forceinline__ float b2f(u16 u) {
  union { u32 i; float f; } c; c.i = ((u32)u) << 16; return c.f;
}
__device__ __forceinline__ u16 f2b(float f) {
  union { float f; u32 i; } c; c.f = f;
  u32 x = c.i;
  u32 r = (x + 0x7fffu + ((x >> 16) & 1u)) >> 16;
  return (u16)r;
}

// ---------------- RMSNorm: xn = bf16(x * rsqrt(mean(x^2)+1e-6) * g) ----------
__global__ __launch_bounds__(256) void rms_kernel(const float* __restrict__ x,
                                                  const float* __restrict__ g,
                                                  u16* __restrict__ xn) {
  int row = blockIdx.x;
  int tid = threadIdx.x;
  float4 v = ((const float4*)(x + (size_t)row * DD))[tid];
  float ss = v.x*v.x + v.y*v.y + v.z*v.z + v.w*v.w;
  for (int off = 32; off; off >>= 1) ss += __shfl_xor(ss, off);
  __shared__ float red[4];
  if ((tid & 63) == 0) red[tid >> 6] = ss;
  __syncthreads();
  float tot = red[0] + red[1] + red[2] + red[3];
  float inv = rsqrtf(tot * (1.0f / DD) + 1e-6f);
  float4 gv = ((const float4*)g)[tid];
  ushort4 o;
  o.x = f2b(v.x * inv * gv.x);
  o.y = f2b(v.y * inv * gv.y);
  o.z = f2b(v.z * inv * gv.z);
  o.w = f2b(v.w * inv * gv.w);
  ((ushort4*)(xn + (size_t)row * DD))[tid] = o;
}

// ---------------- LayerNorm (fp32 in, bf16 out) ----------------
__global__ __launch_bounds__(256) void ln_kernel(const float* __restrict__ a,
                                                 const float* __restrict__ g,
                                                 const float* __restrict__ be,
                                                 u16* __restrict__ o) {
  int row = blockIdx.x;
  int tid = threadIdx.x;
  float4 v = ((const float4*)(a + (size_t)row * DD))[tid];
  float s1 = v.x + v.y + v.z + v.w;
  float s2 = v.x*v.x + v.y*v.y + v.z*v.z + v.w*v.w;
  for (int off = 32; off; off >>= 1) {
    s1 += __shfl_xor(s1, off);
    s2 += __shfl_xor(s2, off);
  }
  __shared__ float r1[4], r2[4];
  if ((tid & 63) == 0) { r1[tid >> 6] = s1; r2[tid >> 6] = s2; }
  __syncthreads();
  float S1 = r1[0] + r1[1] + r1[2] + r1[3];
  float S2 = r2[0] + r2[1] + r2[2] + r2[3];
  float mean = S1 * (1.0f / DD);
  float var  = S2 * (1.0f / DD) - mean * mean;
  float inv  = rsqrtf(var + 1e-5f);
  float4 gv = ((const float4*)g)[tid];
  float4 bv = ((const float4*)be)[tid];
  ushort4 out;
  out.x = f2b((v.x - mean) * inv * gv.x + bv.x);
  out.y = f2b((v.y - mean) * inv * gv.y + bv.y);
  out.z = f2b((v.z - mean) * inv * gv.z + bv.z);
  out.w = f2b((v.w - mean) * inv * gv.w + bv.w);
  ((ushort4*)(o + (size_t)row * DD))[tid] = out;
}

// ------------- q scale: (log2e/sqrt(H)) * softplus(per_dim_scale) -------------
__global__ void scale_kernel(const float* __restrict__ pds, float* __restrict__ qs) {
  int h = threadIdx.x;  // 64
  float p = pds[h];
  float sp = (p > 0.f) ? (p + log1pf(__expf(-p))) : log1pf(__expf(p));
  qs[h] = 0.18033688011112042f * sp;  // LOG2E / sqrt(64)
}

// ---------------- Generic tiled GEMM (bf16 A from ws, fp32 B weights) ----------
// C[M,N] = A[M,K] @ B + bias (+ qscale) (+relu) (+resid fp32)
// TRANSB=false: B is [K,N] ;  TRANSB=true: B is [N,K]
template <bool TRANSB, typename OUT_T>
__global__ __launch_bounds__(256) void gemm_kernel(
    const u16* __restrict__ A, const float* __restrict__ Bw,
    const float* __restrict__ bias, const float* __restrict__ resid,
    const float* __restrict__ qscale, OUT_T* __restrict__ C,
    int M, int N, int K, int relu) {
  __shared__ float As[64][17];   // [m][k]
  __shared__ float Bs[16][65];   // [k][n]
  int tid = threadIdx.x;
  int tx = tid & 15, ty = tid >> 4;
  int row0 = blockIdx.y * 64, col0 = blockIdx.x * 64;
  float acc[4][4] = {};
  for (int k0 = 0; k0 < K; k0 += 16) {
    {
      int r = tid >> 2, kk = (tid & 3) << 2;
      ushort4 a4 = *(const ushort4*)(A + (size_t)(row0 + r) * K + k0 + kk);
      As[r][kk + 0] = b2f(a4.x); As[r][kk + 1] = b2f(a4.y);
      As[r][kk + 2] = b2f(a4.z); As[r][kk + 3] = b2f(a4.w);
    }
    if (!TRANSB) {
      int kk = tid >> 4, c = (tid & 15) << 2;
      float4 b4 = *(const float4*)(Bw + (size_t)(k0 + kk) * N + col0 + c);
      Bs[kk][c + 0] = b4.x; Bs[kk][c + 1] = b4.y;
      Bs[kk][c + 2] = b4.z; Bs[kk][c + 3] = b4.w;
    } else {
      int c = tid >> 2, kk = (tid & 3) << 2;
      float4 b4 = *(const float4*)(Bw + (size_t)(col0 + c) * K + k0 + kk);
      Bs[kk + 0][c] = b4.x; Bs[kk + 1][c] = b4.y;
      Bs[kk + 2][c] = b4.z; Bs[kk + 3][c] = b4.w;
    }
    __syncthreads();
#pragma unroll
    for (int kk = 0; kk < 16; kk++) {
      float a0 = As[ty * 4 + 0][kk], a1 = As[ty * 4 + 1][kk];
      float a2 = As[ty * 4 + 2][kk], a3 = As[ty * 4 + 3][kk];
      float b0 = Bs[kk][tx * 4 + 0], b1 = Bs[kk][tx * 4 + 1];
      float b2 = Bs[kk][tx * 4 + 2], b3 = Bs[kk][tx * 4 + 3];
      acc[0][0] += a0 * b0; acc[0][1] += a0 * b1; acc[0][2] += a0 * b2; acc[0][3] += a0 * b3;
      acc[1][0] += a1 * b0; acc[1][1] += a1 * b1; acc[1][2] += a1 * b2; acc[1][3] += a1 * b3;
      acc[2][0] += a2 * b0; acc[2][1] += a2 * b1; acc[2][2] += a2 * b2; acc[2][3] += a2 * b3;
      acc[3][0] += a3 * b0; acc[3][1] += a3 * b1; acc[3][2] += a3 * b2; acc[3][3] += a3 * b3;
    }
    __syncthreads();
  }
#pragma unroll
  for (int i = 0; i < 4; i++) {
    int r = row0 + ty * 4 + i;
#pragma unroll
    for (int j = 0; j < 4; j++) {
      int c = col0 + tx * 4 + j;
      float v = acc[i][j] + bias[c];
      if (qscale) v *= qscale[c & 63];
      if (relu)   v = fmaxf(v, 0.f);
      if (resid)  v += resid[(size_t)r * N + c];
      if constexpr (sizeof(OUT_T) == 2) ((u16*)C)[(size_t)r * N + c] = f2b(v);
      else                              ((float*)C)[(size_t)r * N + c] = v;
    }
  }
}

// ---------------- Flash-style causal attention (bf16 q/k/v in ws) -------------
// grid: (T/32, G*N); block 256 = 4 waves; wave handles 8 q-rows; K/V tiles of 64
__global__ __launch_bounds__(256) void attn_kernel(
    const u16* __restrict__ q, const u16* __restrict__ k,
    const u16* __restrict__ v, const float* __restrict__ pad,
    u16* __restrict__ ao) {
  int bn = blockIdx.y;
  int b = bn >> 4, n = bn & 15;   // b is chunk-local
  int q0 = blockIdx.x * 32;
  int tid = threadIdx.x;
  int wv = tid >> 6, lane = tid & 63;
  __shared__ float kl[64][65];
  __shared__ float vl[64][65];
  __shared__ float ql[32][65];
  __shared__ float pl[4][8][64];

  for (int i = tid; i < 32 * 64; i += 256) {
    int r = i >> 6, h = i & 63;
    ql[r][h] = b2f(q[((size_t)(b * TT + q0 + r)) * DD + n * HDIM + h]);
  }
  float m_r[8], l_r[8], acc[8], padt[8];
#pragma unroll
  for (int r = 0; r < 8; r++) {
    m_r[r] = -INFINITY; l_r[r] = 0.f; acc[r] = 0.f;
    padt[r] = pad[b * TT + q0 + wv * 8 + r];
  }
  int tmax = q0 + 31;
  for (int s0 = 0; s0 <= tmax; s0 += 64) {
    for (int i = tid; i < 64 * 64; i += 256) {
      int r = i >> 6, h = i & 63;
      size_t gi = ((size_t)(b * TT + s0 + r)) * DD + n * HDIM + h;
      kl[r][h] = b2f(k[gi]);
      vl[r][h] = b2f(v[gi]);
    }
    __syncthreads();
    float pad_s = pad[b * TT + s0 + lane];
#pragma unroll
    for (int r = 0; r < 8; r++) {
      int rl = wv * 8 + r;
      int t = q0 + rl;
      float sc = 0.f;
#pragma unroll
      for (int h = 0; h < 64; h++) sc += ql[rl][h] * kl[lane][h];
      int s = s0 + lane;
      bool valid = (s <= t) && (pad_s != 0.f) && (padt[r] != 0.f);
      sc = valid ? sc : -1e9f;
      float mt = sc;
      for (int off = 32; off; off >>= 1) mt = fmaxf(mt, __shfl_xor(mt, off));
      float mnew = fmaxf(m_r[r], mt);
      float p = __expf(sc - mnew);
      float ps = p;
      for (int off = 32; off; off >>= 1) ps += __shfl_xor(ps, off);
      float alpha = __expf(m_r[r] - mnew);
      l_r[r] = l_r[r] * alpha + ps;
      acc[r] *= alpha;
      m_r[r] = mnew;
      pl[wv][r][lane] = p;
    }
    // pl written and read by the same wave only (in-order DS per wave)
#pragma unroll
    for (int r = 0; r < 8; r++) {
      float a = acc[r];
#pragma unroll 8
      for (int j = 0; j < 64; j++) a += pl[wv][r][j] * vl[j][lane];
      acc[r] = a;
    }
    __syncthreads();
  }
#pragma unroll
  for (int r = 0; r < 8; r++) {
    int t = q0 + wv * 8 + r;
    ao[((size_t)(b * TT + t)) * DD + n * HDIM + lane] = f2b(acc[r] / l_r[r]);
  }
}

extern "C" void kernel_launch(void* const* d_in, const int* in_sizes, int n_in,
                              void* d_out, int out_size, void* d_ws, size_t ws_size,
                              hipStream_t stream) {
  const float* x   = (const float*)d_in[0];
  const float* pad = (const float*)d_in[1];
  const float* rs  = (const float*)d_in[2];
  const float* pds = (const float*)d_in[3];
  const float* wq  = (const float*)d_in[4];
  const float* bq  = (const float*)d_in[5];
  const float* wk  = (const float*)d_in[6];
  const float* bk  = (const float*)d_in[7];
  const float* wv_ = (const float*)d_in[8];
  const float* bv  = (const float*)d_in[9];
  const float* wo  = (const float*)d_in[10];
  const float* bo  = (const float*)d_in[11];
  const float* lg  = (const float*)d_in[12];
  const float* lb  = (const float*)d_in[13];
  const float* w1  = (const float*)d_in[14];
  const float* b1  = (const float*)d_in[15];
  const float* w2  = (const float*)d_in[16];
  const float* b2  = (const float*)d_in[17];
  float* out = (float*)d_out;   // OUTPUT IS FP32 (round-3 diagnosis)

  // Batch-group size G chosen from ws_size: footprint = 8*G MiB (4 regions of 2G MiB)
  const size_t MB = (size_t)1 << 20;
  int G;
  if      (ws_size >= 64 * MB) G = 8;
  else if (ws_size >= 32 * MB) G = 4;
  else if (ws_size >= 16 * MB) G = 2;
  else                         G = 1;

  char* w = (char*)d_ws;
  const size_t SA = (size_t)2 * G * MB;  // one region: G*1024 rows x 1024 bf16
  u16*   regA = (u16*)w;              // xn -> ao -> h1 sub-chunks
  u16*   qB   = (u16*)(w + SA);       // q
  u16*   kC   = (u16*)(w + 2 * SA);   // k
  u16*   vD   = (u16*)(w + 3 * SA);   // v -> hn
  float* att  = (float*)(w + SA);     // fp32, spans regions B+C after q,k dead
  float* qs   = (float*)(w + 3 * SA); // 64 floats, dead before v written
  u16*   hn   = vD;
  u16*   h1   = regA;
  u16*   ao   = regA;

  const int R = G * 1024;  // rows per chunk

  for (int c0 = 0; c0 < BB / G; c0++) {
    size_t rowoff = (size_t)c0 * R;
    const float* xc = x + rowoff * DD;

    rms_kernel<<<R, 256, 0, stream>>>(xc, rs, regA);
    scale_kernel<<<1, 64, 0, stream>>>(pds, qs);

    dim3 gproj(DD / 64, R / 64);
    gemm_kernel<false, u16><<<gproj, 256, 0, stream>>>(
        regA, wq, bq, nullptr, qs, qB, R, DD, DD, 0);
    gemm_kernel<false, u16><<<gproj, 256, 0, stream>>>(
        regA, wk, bk, nullptr, nullptr, kC, R, DD, DD, 0);
    gemm_kernel<false, u16><<<gproj, 256, 0, stream>>>(
        regA, wv_, bv, nullptr, nullptr, vD, R, DD, DD, 0);

    attn_kernel<<<dim3(TT / 32, G * NHEAD), 256, 0, stream>>>(
        qB, kC, vD, pad + rowoff, ao);

    gemm_kernel<true, float><<<gproj, 256, 0, stream>>>(
        ao, wo, bo, xc, nullptr, att, R, DD, DD, 0);

    ln_kernel<<<R, 256, 0, stream>>>(att, lg, lb, hn);

    // FFN in 4 row sub-chunks (h1 sub = R/4 x 4096 bf16 = 2G MiB, fits regA)
    int RS = R / 4;
    for (int s = 0; s < 4; s++) {
      size_t ro = (size_t)s * RS;
      gemm_kernel<false, u16><<<dim3(FF / 64, RS / 64), 256, 0, stream>>>(
          hn + ro * DD, w1, b1, nullptr, nullptr, h1, RS, FF, DD, 1);
      gemm_kernel<false, float><<<dim3(DD / 64, RS / 64), 256, 0, stream>>>(
          h1, w2, b2, att + ro * DD, nullptr, out + (rowoff + ro) * DD, RS, DD, FF, 0);
    }
  }
}

// Round 5
// 2390.150 us; speedup vs baseline: 2.7301x; 2.7301x over previous
//
#include <hip/hip_runtime.h>
#include <hip/hip_bf16.h>
#include <cstdint>
#include <cstddef>

#define BB    8
#define TT    1024
#define DD    1024
#define NHEAD 16
#define HDIM  64
#define FF    4096

typedef unsigned short u16;
typedef unsigned int   u32;
typedef short bf16x8 __attribute__((ext_vector_type(8)));
typedef float floatx4 __attribute__((ext_vector_type(4)));
typedef __attribute__((address_space(1))) const u32 gu32;
typedef __attribute__((address_space(3))) u32 lu32;

__device__ __forceinline__ float b2f(u16 u) {
  union { u32 i; float f; } c; c.i = ((u32)u) << 16; return c.f;
}
__device__ __forceinline__ u16 f2b(float f) {
  union { float f; u32 i; } c; c.f = f;
  u32 x = c.i;
  u32 r = (x + 0x7fffu + ((x >> 16) & 1u)) >> 16;
  return (u16)r;
}

// ---------------- RMSNorm ----------------
__global__ __launch_bounds__(256) void rms_kernel(const float* __restrict__ x,
                                                  const float* __restrict__ g,
                                                  u16* __restrict__ xn) {
  int row = blockIdx.x;
  int tid = threadIdx.x;
  float4 v = ((const float4*)(x + (size_t)row * DD))[tid];
  float ss = v.x*v.x + v.y*v.y + v.z*v.z + v.w*v.w;
  for (int off = 32; off; off >>= 1) ss += __shfl_xor(ss, off);
  __shared__ float red[4];
  if ((tid & 63) == 0) red[tid >> 6] = ss;
  __syncthreads();
  float tot = red[0] + red[1] + red[2] + red[3];
  float inv = rsqrtf(tot * (1.0f / DD) + 1e-6f);
  float4 gv = ((const float4*)g)[tid];
  ushort4 o;
  o.x = f2b(v.x * inv * gv.x);
  o.y = f2b(v.y * inv * gv.y);
  o.z = f2b(v.z * inv * gv.z);
  o.w = f2b(v.w * inv * gv.w);
  ((ushort4*)(xn + (size_t)row * DD))[tid] = o;
}

// ---------------- LayerNorm (fp32 in, bf16 out) ----------------
__global__ __launch_bounds__(256) void ln_kernel(const float* __restrict__ a,
                                                 const float* __restrict__ g,
                                                 const float* __restrict__ be,
                                                 u16* __restrict__ o) {
  int row = blockIdx.x;
  int tid = threadIdx.x;
  float4 v = ((const float4*)(a + (size_t)row * DD))[tid];
  float s1 = v.x + v.y + v.z + v.w;
  float s2 = v.x*v.x + v.y*v.y + v.z*v.z + v.w*v.w;
  for (int off = 32; off; off >>= 1) {
    s1 += __shfl_xor(s1, off);
    s2 += __shfl_xor(s2, off);
  }
  __shared__ float r1[4], r2[4];
  if ((tid & 63) == 0) { r1[tid >> 6] = s1; r2[tid >> 6] = s2; }
  __syncthreads();
  float S1 = r1[0] + r1[1] + r1[2] + r1[3];
  float S2 = r2[0] + r2[1] + r2[2] + r2[3];
  float mean = S1 * (1.0f / DD);
  float var  = S2 * (1.0f / DD) - mean * mean;
  float inv  = rsqrtf(var + 1e-5f);
  float4 gv = ((const float4*)g)[tid];
  float4 bv = ((const float4*)be)[tid];
  ushort4 out;
  out.x = f2b((v.x - mean) * inv * gv.x + bv.x);
  out.y = f2b((v.y - mean) * inv * gv.y + bv.y);
  out.z = f2b((v.z - mean) * inv * gv.z + bv.z);
  out.w = f2b((v.w - mean) * inv * gv.w + bv.w);
  ((ushort4*)(o + (size_t)row * DD))[tid] = out;
}

// ------------- q scale -------------
__global__ void scale_kernel(const float* __restrict__ pds, float* __restrict__ qs) {
  int h = threadIdx.x;
  float p = pds[h];
  float sp = (p > 0.f) ? (p + log1pf(__expf(-p))) : log1pf(__expf(p));
  qs[h] = 0.18033688011112042f * sp;  // LOG2E / sqrt(64)
}

// ------------- weight transpose+convert: in[R][C] fp32 -> out[C][R] bf16 -------
__global__ __launch_bounds__(256) void transpose_conv(const float* __restrict__ in,
                                                      u16* __restrict__ out,
                                                      int R, int C) {
  __shared__ float t[32][33];
  int bx = blockIdx.x * 32, by = blockIdx.y * 32;
  int tx = threadIdx.x & 31, ty = threadIdx.x >> 5;  // 32 x 8
#pragma unroll
  for (int i = 0; i < 32; i += 8)
    t[ty + i][tx] = in[(size_t)(by + ty + i) * C + bx + tx];
  __syncthreads();
#pragma unroll
  for (int i = 0; i < 32; i += 8)
    out[(size_t)(bx + ty + i) * R + by + tx] = f2b(t[tx][ty + i]);
}

// ------------- elementwise fp32 -> bf16 convert -------------
__global__ __launch_bounds__(256) void conv_bf16(const float* __restrict__ in,
                                                 u16* __restrict__ out) {
  int i = blockIdx.x * 256 + threadIdx.x;
  float4 v = ((const float4*)in)[i];
  ushort4 o = { f2b(v.x), f2b(v.y), f2b(v.z), f2b(v.w) };
  ((ushort4*)out)[i] = o;
}

// ---------------- MFMA GEMM (m97 structure) ----------------
// C[M,N] = A[M,K](bf16) @ Bt[N,K](bf16)^T + bias (+qscale) (+relu) (+resid fp32)
// 128x128 tile, BK=32, 256 threads = 4 waves in 2x2; 16 mfma_f32_16x16x32_bf16/K-step
template <typename OUT_T>
__global__ __launch_bounds__(256) void mfma_gemm(
    const u16* __restrict__ A, const u16* __restrict__ Bt,
    const float* __restrict__ bias, const float* __restrict__ resid,
    const float* __restrict__ qscale, OUT_T* __restrict__ C,
    int M, int N, int K, int relu) {
  __shared__ u16 As[128 * 32] __attribute__((aligned(16)));
  __shared__ u16 Bs[128 * 32] __attribute__((aligned(16)));
  int tid = threadIdx.x;
  int lane = tid & 63;
  int wave = tid >> 6;
  int row0 = blockIdx.y * 128, col0 = blockIdx.x * 128;

  // staging: thread t covers tile rows t/4 and t/4+64, k-chunk (t%4)*8 (16 B)
  int sr = tid >> 2;
  int sk = (tid & 3) << 3;
  const u16* ag = A  + (size_t)(row0 + sr) * K + sk;
  const u16* bg = Bt + (size_t)(col0 + sr) * K + sk;
  u16* asl = As + tid * 8;       // byte offset tid*16 == lane-order contiguous
  u16* bsl = Bs + tid * 8;
  size_t rstep = (size_t)64 * K;

  int wr = (wave >> 1) * 64;     // wave row block
  int wc = (wave & 1) * 64;      // wave col block
  int fr = lane & 15;
  int fq = lane >> 4;

  const bf16x8* afp = (const bf16x8*)(As + (size_t)(wr + fr) * 32 + fq * 8);
  const bf16x8* bfp = (const bf16x8*)(Bs + (size_t)(wc + fr) * 32 + fq * 8);

  floatx4 acc[4][4];
#pragma unroll
  for (int mi = 0; mi < 4; mi++)
#pragma unroll
    for (int ni = 0; ni < 4; ni++)
      acc[mi][ni] = (floatx4){0.f, 0.f, 0.f, 0.f};

  for (int k0 = 0; k0 < K; k0 += 32) {
    __builtin_amdgcn_global_load_lds((gu32*)ag,           (lu32*)asl,          16, 0, 0);
    __builtin_amdgcn_global_load_lds((gu32*)(ag + rstep), (lu32*)(asl + 2048), 16, 0, 0);
    __builtin_amdgcn_global_load_lds((gu32*)bg,           (lu32*)bsl,          16, 0, 0);
    __builtin_amdgcn_global_load_lds((gu32*)(bg + rstep), (lu32*)(bsl + 2048), 16, 0, 0);
    __syncthreads();
    bf16x8 af[4], bf[4];
#pragma unroll
    for (int mi = 0; mi < 4; mi++) af[mi] = afp[mi * 64];
#pragma unroll
    for (int ni = 0; ni < 4; ni++) bf[ni] = bfp[ni * 64];
#pragma unroll
    for (int mi = 0; mi < 4; mi++)
#pragma unroll
      for (int ni = 0; ni < 4; ni++)
        acc[mi][ni] = __builtin_amdgcn_mfma_f32_16x16x32_bf16(
            af[mi], bf[ni], acc[mi][ni], 0, 0, 0);
    __syncthreads();
    ag += 32; bg += 32;
  }

#pragma unroll
  for (int mi = 0; mi < 4; mi++) {
    int rbase = row0 + wr + mi * 16 + fq * 4;
#pragma unroll
    for (int ni = 0; ni < 4; ni++) {
      int col = col0 + wc + ni * 16 + fr;
      float bcol = bias[col];
      float qsc = qscale ? qscale[col & 63] : 1.f;
#pragma unroll
      for (int reg = 0; reg < 4; reg++) {
        int r = rbase + reg;
        float v = (acc[mi][ni][reg] + bcol) * qsc;
        if (relu)  v = fmaxf(v, 0.f);
        if (resid) v += resid[(size_t)r * N + col];
        if constexpr (sizeof(OUT_T) == 2) ((u16*)C)[(size_t)r * N + col] = f2b(v);
        else                              ((float*)C)[(size_t)r * N + col] = v;
      }
    }
  }
}

// ---------------- Flash-style causal attention (vectorized LDS reads) ---------
__global__ __launch_bounds__(256) void attn_kernel(
    const u16* __restrict__ q, const u16* __restrict__ k,
    const u16* __restrict__ v, const float* __restrict__ pad,
    u16* __restrict__ ao) {
  int bn = blockIdx.y;
  int b = bn >> 4, n = bn & 15;   // chunk-local batch
  int q0 = blockIdx.x * 32;
  int tid = threadIdx.x;
  int wid = tid >> 6, lane = tid & 63;
  __shared__ float kl[64][66];    // 66: float2-aligned rows, low bank conflict
  __shared__ float vl[64][65];
  __shared__ float ql[32][66];
  __shared__ float pl[4][8][64];

  for (int i = tid; i < 32 * 16; i += 256) {
    int r = i >> 4, h = (i & 15) << 2;
    ushort4 u4 = *(const ushort4*)(q + ((size_t)(b * TT + q0 + r)) * DD + n * HDIM + h);
    ql[r][h] = b2f(u4.x); ql[r][h + 1] = b2f(u4.y);
    ql[r][h + 2] = b2f(u4.z); ql[r][h + 3] = b2f(u4.w);
  }
  float m_r[8], l_r[8], acc[8], padt[8];
#pragma unroll
  for (int r = 0; r < 8; r++) {
    m_r[r] = -INFINITY; l_r[r] = 0.f; acc[r] = 0.f;
    padt[r] = pad[b * TT + q0 + wid * 8 + r];
  }
  int tmax = q0 + 31;
  for (int s0 = 0; s0 <= tmax; s0 += 64) {
    for (int i = tid; i < 64 * 16; i += 256) {
      int r = i >> 4, h = (i & 15) << 2;
      size_t gi = ((size_t)(b * TT + s0 + r)) * DD + n * HDIM + h;
      ushort4 ku = *(const ushort4*)(k + gi);
      ushort4 vu = *(const ushort4*)(v + gi);
      kl[r][h] = b2f(ku.x); kl[r][h + 1] = b2f(ku.y);
      kl[r][h + 2] = b2f(ku.z); kl[r][h + 3] = b2f(ku.w);
      vl[r][h] = b2f(vu.x); vl[r][h + 1] = b2f(vu.y);
      vl[r][h + 2] = b2f(vu.z); vl[r][h + 3] = b2f(vu.w);
    }
    __syncthreads();
    float pad_s = pad[b * TT + s0 + lane];
    const float2* krow = (const float2*)kl[lane];
#pragma unroll
    for (int r = 0; r < 8; r++) {
      int rl = wid * 8 + r;
      int t = q0 + rl;
      const float2* qrow = (const float2*)ql[rl];
      float sx = 0.f, sy = 0.f;
#pragma unroll
      for (int h2 = 0; h2 < 32; h2++) {
        float2 qa = qrow[h2], kb = krow[h2];
        sx += qa.x * kb.x; sy += qa.y * kb.y;
      }
      float sc = sx + sy;
      int s = s0 + lane;
      bool valid = (s <= t) && (pad_s != 0.f) && (padt[r] != 0.f);
      sc = valid ? sc : -1e9f;
      float mt = sc;
      for (int off = 32; off; off >>= 1) mt = fmaxf(mt, __shfl_xor(mt, off));
      float mnew = fmaxf(m_r[r], mt);
      float p = __expf(sc - mnew);
      float ps = p;
      for (int off = 32; off; off >>= 1) ps += __shfl_xor(ps, off);
      float alpha = __expf(m_r[r] - mnew);
      l_r[r] = l_r[r] * alpha + ps;
      acc[r] *= alpha;
      m_r[r] = mnew;
      pl[wid][r][lane] = p;
    }
    // pl written and read by the same wave only (in-order DS per wave)
#pragma unroll
    for (int r = 0; r < 8; r++) {
      const float4* prow = (const float4*)pl[wid][r];
      float a = acc[r];
#pragma unroll
      for (int j4 = 0; j4 < 16; j4++) {
        float4 p4 = prow[j4];
        a += p4.x * vl[j4 * 4 + 0][lane] + p4.y * vl[j4 * 4 + 1][lane]
           + p4.z * vl[j4 * 4 + 2][lane] + p4.w * vl[j4 * 4 + 3][lane];
      }
      acc[r] = a;
    }
    __syncthreads();
  }
#pragma unroll
  for (int r = 0; r < 8; r++) {
    int t = q0 + wid * 8 + r;
    ao[((size_t)(b * TT + t)) * DD + n * HDIM + lane] = f2b(acc[r] / l_r[r]);
  }
}

extern "C" void kernel_launch(void* const* d_in, const int* in_sizes, int n_in,
                              void* d_out, int out_size, void* d_ws, size_t ws_size,
                              hipStream_t stream) {
  const float* x   = (const float*)d_in[0];
  const float* pad = (const float*)d_in[1];
  const float* rs  = (const float*)d_in[2];
  const float* pds = (const float*)d_in[3];
  const float* wq  = (const float*)d_in[4];
  const float* bq  = (const float*)d_in[5];
  const float* wk  = (const float*)d_in[6];
  const float* bk  = (const float*)d_in[7];
  const float* wv_ = (const float*)d_in[8];
  const float* bv  = (const float*)d_in[9];
  const float* wo  = (const float*)d_in[10];
  const float* bo  = (const float*)d_in[11];
  const float* lg  = (const float*)d_in[12];
  const float* lb  = (const float*)d_in[13];
  const float* w1  = (const float*)d_in[14];
  const float* b1  = (const float*)d_in[15];
  const float* w2  = (const float*)d_in[16];
  const float* b2  = (const float*)d_in[17];
  float* out = (float*)d_out;   // fp32 output

  const size_t MB = (size_t)1 << 20;
  // footprint = 24 MB (bf16 weights) + 8G MB (activations)
  int G;
  if      (ws_size >= 88 * MB) G = 8;
  else if (ws_size >= 56 * MB) G = 4;
  else if (ws_size >= 40 * MB) G = 2;
  else                         G = 1;

  char* w = (char*)d_ws;
  u16* wqT = (u16*)(w);             // [1024][1024] bf16, [n][k]
  u16* wkT = (u16*)(w + 2 * MB);
  u16* wvT = (u16*)(w + 4 * MB);
  u16* woT = (u16*)(w + 6 * MB);    // wo is already [d][nh] = [n][k]
  u16* w1T = (u16*)(w + 8 * MB);    // [4096][1024]
  u16* w2T = (u16*)(w + 16 * MB);   // [1024][4096]
  char* act = w + 24 * MB;
  const size_t SA = (size_t)2 * G * MB;   // G*1024 rows x 1024 bf16
  u16*   regA = (u16*)act;            // xn -> ao -> h1
  u16*   qB   = (u16*)(act + SA);
  u16*   kC   = (u16*)(act + 2 * SA);
  u16*   vD   = (u16*)(act + 3 * SA); // v -> hn
  float* att  = (float*)(act + SA);   // fp32, spans qB+kC after q,k dead
  float* qs   = (float*)vD;           // 64 floats, consumed before v written
  u16*   hn   = vD;
  u16*   h1   = regA;
  u16*   ao   = regA;

  // ---- weights -> bf16 [N][K] (every launch; no persistent state allowed) ----
  transpose_conv<<<dim3(32, 32),  256, 0, stream>>>(wq, wqT, DD, DD);
  transpose_conv<<<dim3(32, 32),  256, 0, stream>>>(wk, wkT, DD, DD);
  transpose_conv<<<dim3(32, 32),  256, 0, stream>>>(wv_, wvT, DD, DD);
  conv_bf16<<<1024, 256, 0, stream>>>(wo, woT);
  transpose_conv<<<dim3(128, 32), 256, 0, stream>>>(w1, w1T, DD, FF);
  transpose_conv<<<dim3(32, 128), 256, 0, stream>>>(w2, w2T, FF, DD);

  const int R = G * 1024;

  for (int c0 = 0; c0 < BB / G; c0++) {
    size_t rowoff = (size_t)c0 * R;
    const float* xc = x + rowoff * DD;

    rms_kernel<<<R, 256, 0, stream>>>(xc, rs, regA);
    scale_kernel<<<1, 64, 0, stream>>>(pds, qs);

    dim3 gproj(DD / 128, R / 128);
    mfma_gemm<u16><<<gproj, 256, 0, stream>>>(
        regA, wqT, bq, nullptr, qs, qB, R, DD, DD, 0);
    mfma_gemm<u16><<<gproj, 256, 0, stream>>>(
        regA, wkT, bk, nullptr, nullptr, kC, R, DD, DD, 0);
    mfma_gemm<u16><<<gproj, 256, 0, stream>>>(
        regA, wvT, bv, nullptr, nullptr, vD, R, DD, DD, 0);

    attn_kernel<<<dim3(TT / 32, G * NHEAD), 256, 0, stream>>>(
        qB, kC, vD, pad + rowoff, ao);

    mfma_gemm<float><<<gproj, 256, 0, stream>>>(
        ao, woT, bo, xc, nullptr, att, R, DD, DD, 0);

    ln_kernel<<<R, 256, 0, stream>>>(att, lg, lb, hn);

    int RS = R / 4;  // FFN row sub-chunks: h1 = RS x 4096 bf16 fits regA
    for (int s = 0; s < 4; s++) {
      size_t ro = (size_t)s * RS;
      mfma_gemm<u16><<<dim3(FF / 128, RS / 128), 256, 0, stream>>>(
          hn + ro * DD, w1T, b1, nullptr, nullptr, h1, RS, FF, DD, 1);
      mfma_gemm<float><<<dim3(DD / 128, RS / 128), 256, 0, stream>>>(
          h1, w2T, b2, att + ro * DD, nullptr, out + (rowoff + ro) * DD, RS, DD, FF, 0);
    }
  }
}

// Round 6
// 970.126 us; speedup vs baseline: 6.7264x; 2.4638x over previous
//
#include <hip/hip_runtime.h>
#include <hip/hip_bf16.h>
#include <cstdint>
#include <cstddef>

#define BB    8
#define TT    1024
#define DD    1024
#define NHEAD 16
#define HDIM  64
#define FF    4096

typedef unsigned short u16;
typedef unsigned int   u32;
typedef short bf16x8 __attribute__((ext_vector_type(8)));
typedef float floatx4 __attribute__((ext_vector_type(4)));
typedef float floatx16 __attribute__((ext_vector_type(16)));
typedef __attribute__((address_space(1))) const u32 gu32;
typedef __attribute__((address_space(3))) u32 lu32;

#define ZERO16 {0.f,0.f,0.f,0.f,0.f,0.f,0.f,0.f,0.f,0.f,0.f,0.f,0.f,0.f,0.f,0.f}

__device__ __forceinline__ float b2f(u16 u) {
  union { u32 i; float f; } c; c.i = ((u32)u) << 16; return c.f;
}
__device__ __forceinline__ u16 f2b(float f) {
  union { float f; u32 i; } c; c.f = f;
  u32 x = c.i;
  u32 r = (x + 0x7fffu + ((x >> 16) & 1u)) >> 16;
  return (u16)r;
}

// ---------------- RMSNorm ----------------
__global__ __launch_bounds__(256) void rms_kernel(const float* __restrict__ x,
                                                  const float* __restrict__ g,
                                                  u16* __restrict__ xn) {
  int row = blockIdx.x;
  int tid = threadIdx.x;
  float4 v = ((const float4*)(x + (size_t)row * DD))[tid];
  float ss = v.x*v.x + v.y*v.y + v.z*v.z + v.w*v.w;
  for (int off = 32; off; off >>= 1) ss += __shfl_xor(ss, off);
  __shared__ float red[4];
  if ((tid & 63) == 0) red[tid >> 6] = ss;
  __syncthreads();
  float tot = red[0] + red[1] + red[2] + red[3];
  float inv = rsqrtf(tot * (1.0f / DD) + 1e-6f);
  float4 gv = ((const float4*)g)[tid];
  ushort4 o;
  o.x = f2b(v.x * inv * gv.x);
  o.y = f2b(v.y * inv * gv.y);
  o.z = f2b(v.z * inv * gv.z);
  o.w = f2b(v.w * inv * gv.w);
  ((ushort4*)(xn + (size_t)row * DD))[tid] = o;
}

// ---------------- LayerNorm (fp32 in, bf16 out) ----------------
__global__ __launch_bounds__(256) void ln_kernel(const float* __restrict__ a,
                                                 const float* __restrict__ g,
                                                 const float* __restrict__ be,
                                                 u16* __restrict__ o) {
  int row = blockIdx.x;
  int tid = threadIdx.x;
  float4 v = ((const float4*)(a + (size_t)row * DD))[tid];
  float s1 = v.x + v.y + v.z + v.w;
  float s2 = v.x*v.x + v.y*v.y + v.z*v.z + v.w*v.w;
  for (int off = 32; off; off >>= 1) {
    s1 += __shfl_xor(s1, off);
    s2 += __shfl_xor(s2, off);
  }
  __shared__ float r1[4], r2[4];
  if ((tid & 63) == 0) { r1[tid >> 6] = s1; r2[tid >> 6] = s2; }
  __syncthreads();
  float S1 = r1[0] + r1[1] + r1[2] + r1[3];
  float S2 = r2[0] + r2[1] + r2[2] + r2[3];
  float mean = S1 * (1.0f / DD);
  float var  = S2 * (1.0f / DD) - mean * mean;
  float inv  = rsqrtf(var + 1e-5f);
  float4 gv = ((const float4*)g)[tid];
  float4 bv = ((const float4*)be)[tid];
  ushort4 out;
  out.x = f2b((v.x - mean) * inv * gv.x + bv.x);
  out.y = f2b((v.y - mean) * inv * gv.y + bv.y);
  out.z = f2b((v.z - mean) * inv * gv.z + bv.z);
  out.w = f2b((v.w - mean) * inv * gv.w + bv.w);
  ((ushort4*)(o + (size_t)row * DD))[tid] = out;
}

// ------------- q scale -------------
__global__ void scale_kernel(const float* __restrict__ pds, float* __restrict__ qs) {
  int h = threadIdx.x;
  float p = pds[h];
  float sp = (p > 0.f) ? (p + log1pf(__expf(-p))) : log1pf(__expf(p));
  qs[h] = 0.18033688011112042f * sp;  // LOG2E / sqrt(64)
}

// ------------- weight transpose+convert: in[R][C] fp32 -> out[C][R] bf16 -------
__global__ __launch_bounds__(256) void transpose_conv(const float* __restrict__ in,
                                                      u16* __restrict__ out,
                                                      int R, int C) {
  __shared__ float t[32][33];
  int bx = blockIdx.x * 32, by = blockIdx.y * 32;
  int tx = threadIdx.x & 31, ty = threadIdx.x >> 5;  // 32 x 8
#pragma unroll
  for (int i = 0; i < 32; i += 8)
    t[ty + i][tx] = in[(size_t)(by + ty + i) * C + bx + tx];
  __syncthreads();
#pragma unroll
  for (int i = 0; i < 32; i += 8)
    out[(size_t)(bx + ty + i) * R + by + tx] = f2b(t[tx][ty + i]);
}

// ------------- elementwise fp32 -> bf16 convert -------------
__global__ __launch_bounds__(256) void conv_bf16(const float* __restrict__ in,
                                                 u16* __restrict__ out) {
  int i = blockIdx.x * 256 + threadIdx.x;
  float4 v = ((const float4*)in)[i];
  ushort4 o = { f2b(v.x), f2b(v.y), f2b(v.z), f2b(v.w) };
  ((ushort4*)out)[i] = o;
}

// ------------- V transpose per (b,n): vdst[bn][h][t] = vsrc[b*T+t][n*64+h] ----
__global__ __launch_bounds__(256) void vtrans_kernel(const u16* __restrict__ vsrc,
                                                     u16* __restrict__ vdst) {
  __shared__ u16 tile[64][65];
  int bn = blockIdx.y; int b = bn >> 4, n = bn & 15;
  int t0 = blockIdx.x * 64;
  int tid = threadIdx.x;
  int rr = tid >> 4;        // 0..15
  int c4 = (tid & 15) * 4;  // 0..60
#pragma unroll
  for (int i = 0; i < 4; i++) {
    int r = i * 16 + rr;    // token row in tile
    ushort4 d = *(const ushort4*)(vsrc + ((size_t)(b * TT + t0 + r)) * DD + n * HDIM + c4);
    tile[r][c4 + 0] = d.x; tile[r][c4 + 1] = d.y;
    tile[r][c4 + 2] = d.z; tile[r][c4 + 3] = d.w;
  }
  __syncthreads();
#pragma unroll
  for (int i = 0; i < 4; i++) {
    int h = i * 16 + rr;
    ushort4 d;
    d.x = tile[c4 + 0][h]; d.y = tile[c4 + 1][h];
    d.z = tile[c4 + 2][h]; d.w = tile[c4 + 3][h];
    *(ushort4*)(vdst + ((size_t)bn * HDIM + h) * TT + t0 + c4) = d;
  }
}

// ---------------- MFMA GEMM (m97 structure) ----------------
template <typename OUT_T>
__global__ __launch_bounds__(256) void mfma_gemm(
    const u16* __restrict__ A, const u16* __restrict__ Bt,
    const float* __restrict__ bias, const float* __restrict__ resid,
    const float* __restrict__ qscale, OUT_T* __restrict__ C,
    int M, int N, int K, int relu) {
  __shared__ u16 As[128 * 32] __attribute__((aligned(16)));
  __shared__ u16 Bs[128 * 32] __attribute__((aligned(16)));
  int tid = threadIdx.x;
  int lane = tid & 63;
  int wave = tid >> 6;
  int row0 = blockIdx.y * 128, col0 = blockIdx.x * 128;

  int sr = tid >> 2;
  int sk = (tid & 3) << 3;
  const u16* ag = A  + (size_t)(row0 + sr) * K + sk;
  const u16* bg = Bt + (size_t)(col0 + sr) * K + sk;
  u16* asl = As + tid * 8;
  u16* bsl = Bs + tid * 8;
  size_t rstep = (size_t)64 * K;

  int wr = (wave >> 1) * 64;
  int wc = (wave & 1) * 64;
  int fr = lane & 15;
  int fq = lane >> 4;

  const bf16x8* afp = (const bf16x8*)(As + (size_t)(wr + fr) * 32 + fq * 8);
  const bf16x8* bfp = (const bf16x8*)(Bs + (size_t)(wc + fr) * 32 + fq * 8);

  floatx4 acc[4][4];
#pragma unroll
  for (int mi = 0; mi < 4; mi++)
#pragma unroll
    for (int ni = 0; ni < 4; ni++)
      acc[mi][ni] = (floatx4){0.f, 0.f, 0.f, 0.f};

  for (int k0 = 0; k0 < K; k0 += 32) {
    __builtin_amdgcn_global_load_lds((gu32*)ag,           (lu32*)asl,          16, 0, 0);
    __builtin_amdgcn_global_load_lds((gu32*)(ag + rstep), (lu32*)(asl + 2048), 16, 0, 0);
    __builtin_amdgcn_global_load_lds((gu32*)bg,           (lu32*)bsl,          16, 0, 0);
    __builtin_amdgcn_global_load_lds((gu32*)(bg + rstep), (lu32*)(bsl + 2048), 16, 0, 0);
    __syncthreads();
    bf16x8 af[4], bf[4];
#pragma unroll
    for (int mi = 0; mi < 4; mi++) af[mi] = afp[mi * 64];
#pragma unroll
    for (int ni = 0; ni < 4; ni++) bf[ni] = bfp[ni * 64];
#pragma unroll
    for (int mi = 0; mi < 4; mi++)
#pragma unroll
      for (int ni = 0; ni < 4; ni++)
        acc[mi][ni] = __builtin_amdgcn_mfma_f32_16x16x32_bf16(
            af[mi], bf[ni], acc[mi][ni], 0, 0, 0);
    __syncthreads();
    ag += 32; bg += 32;
  }

#pragma unroll
  for (int mi = 0; mi < 4; mi++) {
    int rbase = row0 + wr + mi * 16 + fq * 4;
#pragma unroll
    for (int ni = 0; ni < 4; ni++) {
      int col = col0 + wc + ni * 16 + fr;
      float bcol = bias[col];
      float qsc = qscale ? qscale[col & 63] : 1.f;
#pragma unroll
      for (int reg = 0; reg < 4; reg++) {
        int r = rbase + reg;
        float v = (acc[mi][ni][reg] + bcol) * qsc;
        if (relu)  v = fmaxf(v, 0.f);
        if (resid) v += resid[(size_t)r * N + col];
        if constexpr (sizeof(OUT_T) == 2) ((u16*)C)[(size_t)r * N + col] = f2b(v);
        else                              ((float*)C)[(size_t)r * N + col] = v;
      }
    }
  }
}

// ---------------- MFMA flash attention ----------------
// Block: 128 q-rows of one (b,n); 4 waves, wave w -> qrows 32w..32w+31.
// S^T = K @ Q^T (C-layout: col=qrow, row=key) -> in-register softmax over keys
// O^T = V^T @ P^T (P^T B-frag assembled from registers via lane^32 exchange)
// LDS tiles XOR-swizzled: chunk c of row r stored at c^(r&7) (8 chunks/row).
__global__ __launch_bounds__(256) void attn_mfma(
    const u16* __restrict__ q, const u16* __restrict__ k,
    const u16* __restrict__ vT, const float* __restrict__ padc,
    u16* __restrict__ ao) {
  int bn = blockIdx.y; int b = bn >> 4, n = bn & 15;
  int q0g = blockIdx.x * 128;
  int tid = threadIdx.x;
  int w = tid >> 6, lane = tid & 63;
  int cl = lane & 31, hf = lane >> 5;
  __shared__ u16 Qs[128 * 64] __attribute__((aligned(16)));
  __shared__ u16 Ks[64 * 64]  __attribute__((aligned(16)));
  __shared__ u16 Vts[64 * 64] __attribute__((aligned(16)));
  __shared__ float padl[64];

  // stage Q tile (128 rows x 64 h), swizzled
#pragma unroll
  for (int it = 0; it < 4; it++) {
    int cid = it * 256 + tid; int r = cid >> 3, cc = cid & 7;
    uint4 d = *(const uint4*)(q + ((size_t)(b * TT + q0g + r)) * DD + n * HDIM + cc * 8);
    ((uint4*)Qs)[r * 8 + (cc ^ (r & 7))] = d;
  }
  __syncthreads();
  bf16x8 qf[4];
  int qrow = 32 * w + cl;
#pragma unroll
  for (int kc = 0; kc < 4; kc++)
    qf[kc] = ((const bf16x8*)Qs)[qrow * 8 + ((2 * kc + hf) ^ (cl & 7))];

  int tq = q0g + qrow;
  float prow = padc[b * TT + tq];
  bool prow_ok = (prow != 0.f);
  floatx16 o0 = ZERO16, o1 = ZERO16;
  float m_i = -INFINITY, l_i = 0.f;

  int jend = q0g + 128;
  for (int j0 = 0; j0 < jend; j0 += 64) {
    // stage K tile [64 key][64 h] and Vt tile [64 h][64 key], swizzled
#pragma unroll
    for (int it = 0; it < 2; it++) {
      int cid = it * 256 + tid; int r = cid >> 3, cc = cid & 7;
      uint4 dk = *(const uint4*)(k + ((size_t)(b * TT + j0 + r)) * DD + n * HDIM + cc * 8);
      ((uint4*)Ks)[r * 8 + (cc ^ (r & 7))] = dk;
      uint4 dv = *(const uint4*)(vT + ((size_t)(bn * HDIM + r)) * TT + j0 + cc * 8);
      ((uint4*)Vts)[r * 8 + (cc ^ (r & 7))] = dv;
    }
    if (tid < 64) padl[tid] = padc[b * TT + j0 + tid];
    __syncthreads();

    // S^T = K @ Q^T : s0 = keys j0+0..31, s1 = keys j0+32..63 (cols = qrows)
    floatx16 s0 = ZERO16, s1 = ZERO16;
#pragma unroll
    for (int kc = 0; kc < 4; kc++) {
      bf16x8 ka0 = ((const bf16x8*)Ks)[cl * 8 + ((2 * kc + hf) ^ (cl & 7))];
      bf16x8 ka1 = ((const bf16x8*)Ks)[(32 + cl) * 8 + ((2 * kc + hf) ^ (cl & 7))];
      s0 = __builtin_amdgcn_mfma_f32_32x32x16_bf16(ka0, qf[kc], s0, 0, 0, 0);
      s1 = __builtin_amdgcn_mfma_f32_32x32x16_bf16(ka1, qf[kc], s1, 0, 0, 0);
    }

    // mask: key = 32*q2 + 8*rg + 4*hf + j  (reg = 4*rg + j)
    float mloc = -INFINITY;
#pragma unroll
    for (int q2 = 0; q2 < 2; q2++) {
#pragma unroll
      for (int rg = 0; rg < 4; rg++) {
        float4 pv = *(const float4*)&padl[q2 * 32 + rg * 8 + 4 * hf];
        int kb = j0 + q2 * 32 + rg * 8 + 4 * hf;
#pragma unroll
        for (int j = 0; j < 4; j++) {
          int idx = rg * 4 + j;
          float sval = q2 ? s1[idx] : s0[idx];
          float pvj = (j == 0) ? pv.x : (j == 1) ? pv.y : (j == 2) ? pv.z : pv.w;
          bool ok = prow_ok && (kb + j <= tq) && (pvj != 0.f);
          sval = ok ? sval : -1e9f;
          if (q2) s1[idx] = sval; else s0[idx] = sval;
          mloc = fmaxf(mloc, sval);
        }
      }
    }
    float mtile = fmaxf(mloc, __shfl_xor(mloc, 32));
    float mnew = fmaxf(m_i, mtile);
    float alpha = __expf(m_i - mnew);
    m_i = mnew;
    float ls = 0.f;
#pragma unroll
    for (int i = 0; i < 16; i++) {
      float p0 = __expf(s0[i] - mnew); s0[i] = p0; ls += p0;
      float p1 = __expf(s1[i] - mnew); s1[i] = p1; ls += p1;
    }
    ls += __shfl_xor(ls, 32);
    l_i = l_i * alpha + ls;
    o0 *= alpha; o1 *= alpha;

    // pack p into bf16 pairs: block be=4*q2+rg covers 4 consecutive keys
    u32 pk[8][2];
#pragma unroll
    for (int q2 = 0; q2 < 2; q2++)
#pragma unroll
      for (int rg = 0; rg < 4; rg++) {
        int be = q2 * 4 + rg;
        float a0 = q2 ? s1[rg * 4 + 0] : s0[rg * 4 + 0];
        float a1 = q2 ? s1[rg * 4 + 1] : s0[rg * 4 + 1];
        float a2 = q2 ? s1[rg * 4 + 2] : s0[rg * 4 + 2];
        float a3 = q2 ? s1[rg * 4 + 3] : s0[rg * 4 + 3];
        pk[be][0] = (u32)f2b(a0) | ((u32)f2b(a1) << 16);
        pk[be][1] = (u32)f2b(a2) | ((u32)f2b(a3) << 16);
      }
    u32 pp[8][2];
#pragma unroll
    for (int be = 0; be < 8; be++) {
      pp[be][0] = (u32)__shfl_xor((int)pk[be][0], 32);
      pp[be][1] = (u32)__shfl_xor((int)pk[be][1], 32);
    }

    // O^T += V^T @ P^T
#pragma unroll
    for (int kc = 0; kc < 4; kc++) {
      union { u32 wd[4]; bf16x8 v; } pb;
      if (hf == 0) {
        pb.wd[0] = pk[2 * kc][0];     pb.wd[1] = pk[2 * kc][1];
        pb.wd[2] = pp[2 * kc][0];     pb.wd[3] = pp[2 * kc][1];
      } else {
        pb.wd[0] = pp[2 * kc + 1][0]; pb.wd[1] = pp[2 * kc + 1][1];
        pb.wd[2] = pk[2 * kc + 1][0]; pb.wd[3] = pk[2 * kc + 1][1];
      }
      bf16x8 vf0 = ((const bf16x8*)Vts)[cl * 8 + ((2 * kc + hf) ^ (cl & 7))];
      bf16x8 vf1 = ((const bf16x8*)Vts)[(32 + cl) * 8 + ((2 * kc + hf) ^ (cl & 7))];
      o0 = __builtin_amdgcn_mfma_f32_32x32x16_bf16(vf0, pb.v, o0, 0, 0, 0);
      o1 = __builtin_amdgcn_mfma_f32_32x32x16_bf16(vf1, pb.v, o1, 0, 0, 0);
    }
    __syncthreads();
  }

  float rl = 1.f / l_i;
  // O^T C-layout: row=hdim=(reg&3)+8*(reg>>2)+4*hf (+32 for o1), col=qrow=cl
#pragma unroll
  for (int hq = 0; hq < 2; hq++)
#pragma unroll
    for (int rg = 0; rg < 4; rg++) {
      ushort4 st;
      st.x = f2b((hq ? o1[rg * 4 + 0] : o0[rg * 4 + 0]) * rl);
      st.y = f2b((hq ? o1[rg * 4 + 1] : o0[rg * 4 + 1]) * rl);
      st.z = f2b((hq ? o1[rg * 4 + 2] : o0[rg * 4 + 2]) * rl);
      st.w = f2b((hq ? o1[rg * 4 + 3] : o0[rg * 4 + 3]) * rl);
      int col = n * HDIM + hq * 32 + rg * 8 + 4 * hf;
      *(ushort4*)(ao + ((size_t)(b * TT + tq)) * DD + col) = st;
    }
}

extern "C" void kernel_launch(void* const* d_in, const int* in_sizes, int n_in,
                              void* d_out, int out_size, void* d_ws, size_t ws_size,
                              hipStream_t stream) {
  const float* x   = (const float*)d_in[0];
  const float* pad = (const float*)d_in[1];
  const float* rs  = (const float*)d_in[2];
  const float* pds = (const float*)d_in[3];
  const float* wq  = (const float*)d_in[4];
  const float* bq  = (const float*)d_in[5];
  const float* wk  = (const float*)d_in[6];
  const float* bk  = (const float*)d_in[7];
  const float* wv_ = (const float*)d_in[8];
  const float* bv  = (const float*)d_in[9];
  const float* wo  = (const float*)d_in[10];
  const float* bo  = (const float*)d_in[11];
  const float* lg  = (const float*)d_in[12];
  const float* lb  = (const float*)d_in[13];
  const float* w1  = (const float*)d_in[14];
  const float* b1  = (const float*)d_in[15];
  const float* w2  = (const float*)d_in[16];
  const float* b2  = (const float*)d_in[17];
  float* out = (float*)d_out;   // fp32 output

  const size_t MB = (size_t)1 << 20;
  int G;
  if      (ws_size >= 88 * MB) G = 8;
  else if (ws_size >= 56 * MB) G = 4;
  else if (ws_size >= 40 * MB) G = 2;
  else                         G = 1;

  char* w = (char*)d_ws;
  u16* wqT = (u16*)(w);
  u16* wkT = (u16*)(w + 2 * MB);
  u16* wvT = (u16*)(w + 4 * MB);
  u16* woT = (u16*)(w + 6 * MB);
  u16* w1T = (u16*)(w + 8 * MB);
  u16* w2T = (u16*)(w + 16 * MB);
  char* act = w + 24 * MB;
  const size_t SA = (size_t)2 * G * MB;
  u16*   regA = (u16*)act;             // xn -> vT -> hn
  u16*   qB   = (u16*)(act + SA);      // q
  u16*   kC   = (u16*)(act + 2 * SA);  // k
  u16*   vD   = (u16*)(act + 3 * SA);  // v -> ao -> h1
  float* att  = (float*)(act + SA);    // fp32, spans qB+kC after q,k dead
  float* qs   = (float*)vD;            // 64 floats, consumed before v written
  u16*   vTr  = regA;
  u16*   ao   = vD;
  u16*   hn   = regA;
  u16*   h1   = vD;

  transpose_conv<<<dim3(32, 32),  256, 0, stream>>>(wq, wqT, DD, DD);
  transpose_conv<<<dim3(32, 32),  256, 0, stream>>>(wk, wkT, DD, DD);
  transpose_conv<<<dim3(32, 32),  256, 0, stream>>>(wv_, wvT, DD, DD);
  conv_bf16<<<1024, 256, 0, stream>>>(wo, woT);
  transpose_conv<<<dim3(128, 32), 256, 0, stream>>>(w1, w1T, DD, FF);
  transpose_conv<<<dim3(32, 128), 256, 0, stream>>>(w2, w2T, FF, DD);

  const int R = G * 1024;

  for (int c0 = 0; c0 < BB / G; c0++) {
    size_t rowoff = (size_t)c0 * R;
    const float* xc = x + rowoff * DD;

    rms_kernel<<<R, 256, 0, stream>>>(xc, rs, regA);
    scale_kernel<<<1, 64, 0, stream>>>(pds, qs);

    dim3 gproj(DD / 128, R / 128);
    mfma_gemm<u16><<<gproj, 256, 0, stream>>>(
        regA, wqT, bq, nullptr, qs, qB, R, DD, DD, 0);
    mfma_gemm<u16><<<gproj, 256, 0, stream>>>(
        regA, wkT, bk, nullptr, nullptr, kC, R, DD, DD, 0);
    mfma_gemm<u16><<<gproj, 256, 0, stream>>>(
        regA, wvT, bv, nullptr, nullptr, vD, R, DD, DD, 0);

    // V -> per-(b,n) transposed layout (xn in regA is dead now)
    vtrans_kernel<<<dim3(TT / 64, G * NHEAD), 256, 0, stream>>>(vD, vTr);

    attn_mfma<<<dim3(TT / 128, G * NHEAD), 256, 0, stream>>>(
        qB, kC, vTr, pad + rowoff, ao);

    mfma_gemm<float><<<gproj, 256, 0, stream>>>(
        ao, woT, bo, xc, nullptr, att, R, DD, DD, 0);

    ln_kernel<<<R, 256, 0, stream>>>(att, lg, lb, hn);

    int RS = R / 4;
    for (int s = 0; s < 4; s++) {
      size_t ro = (size_t)s * RS;
      mfma_gemm<u16><<<dim3(FF / 128, RS / 128), 256, 0, stream>>>(
          hn + ro * DD, w1T, b1, nullptr, nullptr, h1, RS, FF, DD, 1);
      mfma_gemm<float><<<dim3(DD / 128, RS / 128), 256, 0, stream>>>(
          h1, w2T, b2, att + ro * DD, nullptr, out + (rowoff + ro) * DD, RS, DD, FF, 0);
    }
  }
}

// Round 7
// 742.741 us; speedup vs baseline: 8.7856x; 1.3061x over previous
//
#include <hip/hip_runtime.h>
#include <hip/hip_bf16.h>
#include <cstdint>
#include <cstddef>

#define BB    8
#define TT    1024
#define DD    1024
#define NHEAD 16
#define HDIM  64
#define FF    4096

typedef unsigned short u16;
typedef unsigned int   u32;
typedef short bf16x8 __attribute__((ext_vector_type(8)));
typedef float floatx4 __attribute__((ext_vector_type(4)));
typedef float floatx16 __attribute__((ext_vector_type(16)));
typedef __attribute__((address_space(1))) const u32 gu32;
typedef __attribute__((address_space(3))) u32 lu32;

#define ZERO16 {0.f,0.f,0.f,0.f,0.f,0.f,0.f,0.f,0.f,0.f,0.f,0.f,0.f,0.f,0.f,0.f}

__device__ __forceinline__ float b2f(u16 u) {
  union { u32 i; float f; } c; c.i = ((u32)u) << 16; return c.f;
}
__device__ __forceinline__ u16 f2b(float f) {
  union { float f; u32 i; } c; c.f = f;
  u32 x = c.i;
  u32 r = (x + 0x7fffu + ((x >> 16) & 1u)) >> 16;
  return (u16)r;
}

// ---------------- RMSNorm ----------------
__global__ __launch_bounds__(256) void rms_kernel(const float* __restrict__ x,
                                                  const float* __restrict__ g,
                                                  u16* __restrict__ xn) {
  int row = blockIdx.x;
  int tid = threadIdx.x;
  float4 v = ((const float4*)(x + (size_t)row * DD))[tid];
  float ss = v.x*v.x + v.y*v.y + v.z*v.z + v.w*v.w;
  for (int off = 32; off; off >>= 1) ss += __shfl_xor(ss, off);
  __shared__ float red[4];
  if ((tid & 63) == 0) red[tid >> 6] = ss;
  __syncthreads();
  float tot = red[0] + red[1] + red[2] + red[3];
  float inv = rsqrtf(tot * (1.0f / DD) + 1e-6f);
  float4 gv = ((const float4*)g)[tid];
  ushort4 o;
  o.x = f2b(v.x * inv * gv.x);
  o.y = f2b(v.y * inv * gv.y);
  o.z = f2b(v.z * inv * gv.z);
  o.w = f2b(v.w * inv * gv.w);
  ((ushort4*)(xn + (size_t)row * DD))[tid] = o;
}

// ---------------- LayerNorm (fp32 in, bf16 out) ----------------
__global__ __launch_bounds__(256) void ln_kernel(const float* __restrict__ a,
                                                 const float* __restrict__ g,
                                                 const float* __restrict__ be,
                                                 u16* __restrict__ o) {
  int row = blockIdx.x;
  int tid = threadIdx.x;
  float4 v = ((const float4*)(a + (size_t)row * DD))[tid];
  float s1 = v.x + v.y + v.z + v.w;
  float s2 = v.x*v.x + v.y*v.y + v.z*v.z + v.w*v.w;
  for (int off = 32; off; off >>= 1) {
    s1 += __shfl_xor(s1, off);
    s2 += __shfl_xor(s2, off);
  }
  __shared__ float r1[4], r2[4];
  if ((tid & 63) == 0) { r1[tid >> 6] = s1; r2[tid >> 6] = s2; }
  __syncthreads();
  float S1 = r1[0] + r1[1] + r1[2] + r1[3];
  float S2 = r2[0] + r2[1] + r2[2] + r2[3];
  float mean = S1 * (1.0f / DD);
  float var  = S2 * (1.0f / DD) - mean * mean;
  float inv  = rsqrtf(var + 1e-5f);
  float4 gv = ((const float4*)g)[tid];
  float4 bv = ((const float4*)be)[tid];
  ushort4 out;
  out.x = f2b((v.x - mean) * inv * gv.x + bv.x);
  out.y = f2b((v.y - mean) * inv * gv.y + bv.y);
  out.z = f2b((v.z - mean) * inv * gv.z + bv.z);
  out.w = f2b((v.w - mean) * inv * gv.w + bv.w);
  ((ushort4*)(o + (size_t)row * DD))[tid] = out;
}

// ------------- per-column bias+scale arrays for fused QKV -------------
__global__ void prep_kernel(const float* __restrict__ bq, const float* __restrict__ bk,
                            const float* __restrict__ bv, const float* __restrict__ pds,
                            float* __restrict__ bqkv, float* __restrict__ qsall) {
  int j = blockIdx.x * 1024 + threadIdx.x;  // 3 blocks x 1024
  float b = (j < 1024) ? bq[j] : (j < 2048) ? bk[j - 1024] : bv[j - 2048];
  bqkv[j] = b;
  float s = 1.f;
  if (j < 1024) {
    float p = pds[j & 63];
    float sp = (p > 0.f) ? (p + log1pf(__expf(-p))) : log1pf(__expf(p));
    s = 0.18033688011112042f * sp;  // LOG2E/sqrt(64) * softplus
  }
  qsall[j] = s;
}

// ------------- weight transpose+convert: in[R][C] fp32 -> out[C][R] bf16 -------
__global__ __launch_bounds__(256) void transpose_conv(const float* __restrict__ in,
                                                      u16* __restrict__ out,
                                                      int R, int C) {
  __shared__ float t[32][33];
  int bx = blockIdx.x * 32, by = blockIdx.y * 32;
  int tx = threadIdx.x & 31, ty = threadIdx.x >> 5;  // 32 x 8
#pragma unroll
  for (int i = 0; i < 32; i += 8)
    t[ty + i][tx] = in[(size_t)(by + ty + i) * C + bx + tx];
  __syncthreads();
#pragma unroll
  for (int i = 0; i < 32; i += 8)
    out[(size_t)(bx + ty + i) * R + by + tx] = f2b(t[tx][ty + i]);
}

// ------------- elementwise fp32 -> bf16 convert -------------
__global__ __launch_bounds__(256) void conv_bf16(const float* __restrict__ in,
                                                 u16* __restrict__ out) {
  int i = blockIdx.x * 256 + threadIdx.x;
  float4 v = ((const float4*)in)[i];
  ushort4 o = { f2b(v.x), f2b(v.y), f2b(v.z), f2b(v.w) };
  ((ushort4*)out)[i] = o;
}

// ------------- V transpose per (b,n): vdst[bn][h][t] = vsrc[b*T+t][n*64+h] ----
__global__ __launch_bounds__(256) void vtrans_kernel(const u16* __restrict__ vsrc,
                                                     u16* __restrict__ vdst) {
  __shared__ u16 tile[64][65];
  int bn = blockIdx.y; int b = bn >> 4, n = bn & 15;
  int t0 = blockIdx.x * 64;
  int tid = threadIdx.x;
  int rr = tid >> 4;
  int c4 = (tid & 15) * 4;
#pragma unroll
  for (int i = 0; i < 4; i++) {
    int r = i * 16 + rr;
    ushort4 d = *(const ushort4*)(vsrc + ((size_t)(b * TT + t0 + r)) * DD + n * HDIM + c4);
    tile[r][c4 + 0] = d.x; tile[r][c4 + 1] = d.y;
    tile[r][c4 + 2] = d.z; tile[r][c4 + 3] = d.w;
  }
  __syncthreads();
#pragma unroll
  for (int i = 0; i < 4; i++) {
    int h = i * 16 + rr;
    ushort4 d;
    d.x = tile[c4 + 0][h]; d.y = tile[c4 + 1][h];
    d.z = tile[c4 + 2][h]; d.w = tile[c4 + 3][h];
    *(ushort4*)(vdst + ((size_t)bn * HDIM + h) * TT + t0 + c4) = d;
  }
}

// ---------------- MFMA GEMM (m97 structure, strided B, unified epilogue) ------
// C[...] = (A[M,K] @ Bt^T + bias[col]) * scale[col] (+relu) (+accsrc fp32)
// output column col -> C[(col>>10)*regstride + r*1024 + (col&1023)]  (ldc==1024)
template <typename OUT_T>
__global__ __launch_bounds__(256) void mfma_gemm(
    const u16* __restrict__ A, const u16* __restrict__ Bt,
    const float* __restrict__ bias, const float* __restrict__ accsrc,
    const float* __restrict__ scale, OUT_T* __restrict__ C,
    int lda, int ldb, int K, int relu, size_t regstride) {
  __shared__ u16 As[128 * 32] __attribute__((aligned(16)));
  __shared__ u16 Bs[128 * 32] __attribute__((aligned(16)));
  int tid = threadIdx.x;
  int lane = tid & 63;
  int wave = tid >> 6;
  int row0 = blockIdx.y * 128, col0 = blockIdx.x * 128;

  int sr = tid >> 2;
  int sk = (tid & 3) << 3;
  const u16* ag = A  + (size_t)(row0 + sr) * lda + sk;
  const u16* bg = Bt + (size_t)(col0 + sr) * ldb + sk;
  u16* asl = As + tid * 8;
  u16* bsl = Bs + tid * 8;
  size_t rstepA = (size_t)64 * lda;
  size_t rstepB = (size_t)64 * ldb;

  int wr = (wave >> 1) * 64;
  int wc = (wave & 1) * 64;
  int fr = lane & 15;
  int fq = lane >> 4;

  const bf16x8* afp = (const bf16x8*)(As + (size_t)(wr + fr) * 32 + fq * 8);
  const bf16x8* bfp = (const bf16x8*)(Bs + (size_t)(wc + fr) * 32 + fq * 8);

  floatx4 acc[4][4];
#pragma unroll
  for (int mi = 0; mi < 4; mi++)
#pragma unroll
    for (int ni = 0; ni < 4; ni++)
      acc[mi][ni] = (floatx4){0.f, 0.f, 0.f, 0.f};

  for (int k0 = 0; k0 < K; k0 += 32) {
    __builtin_amdgcn_global_load_lds((gu32*)ag,            (lu32*)asl,          16, 0, 0);
    __builtin_amdgcn_global_load_lds((gu32*)(ag + rstepA), (lu32*)(asl + 2048), 16, 0, 0);
    __builtin_amdgcn_global_load_lds((gu32*)bg,            (lu32*)bsl,          16, 0, 0);
    __builtin_amdgcn_global_load_lds((gu32*)(bg + rstepB), (lu32*)(bsl + 2048), 16, 0, 0);
    __syncthreads();
    bf16x8 af[4], bf[4];
#pragma unroll
    for (int mi = 0; mi < 4; mi++) af[mi] = afp[mi * 64];
#pragma unroll
    for (int ni = 0; ni < 4; ni++) bf[ni] = bfp[ni * 64];
#pragma unroll
    for (int mi = 0; mi < 4; mi++)
#pragma unroll
      for (int ni = 0; ni < 4; ni++)
        acc[mi][ni] = __builtin_amdgcn_mfma_f32_16x16x32_bf16(
            af[mi], bf[ni], acc[mi][ni], 0, 0, 0);
    __syncthreads();
    ag += 32; bg += 32;
  }

#pragma unroll
  for (int mi = 0; mi < 4; mi++) {
    int rbase = row0 + wr + mi * 16 + fq * 4;
#pragma unroll
    for (int ni = 0; ni < 4; ni++) {
      int col = col0 + wc + ni * 16 + fr;
      float bcol = bias ? bias[col] : 0.f;
      float scl  = scale ? scale[col] : 1.f;
      size_t cbase = (size_t)(col >> 10) * regstride + (col & 1023);
#pragma unroll
      for (int reg = 0; reg < 4; reg++) {
        int r = rbase + reg;
        float v = (acc[mi][ni][reg] + bcol) * scl;
        if (relu)   v = fmaxf(v, 0.f);
        if (accsrc) v += accsrc[(size_t)r * 1024 + col];
        if constexpr (sizeof(OUT_T) == 2) ((u16*)C)[cbase + (size_t)r * 1024] = f2b(v);
        else                              ((float*)C)[cbase + (size_t)r * 1024] = v;
      }
    }
  }
}

// ---------------- MFMA flash attention (round-6 verified) ----------------
__global__ __launch_bounds__(256) void attn_mfma(
    const u16* __restrict__ q, const u16* __restrict__ k,
    const u16* __restrict__ vT, const float* __restrict__ padc,
    u16* __restrict__ ao) {
  int bn = blockIdx.y; int b = bn >> 4, n = bn & 15;
  int q0g = blockIdx.x * 128;
  int tid = threadIdx.x;
  int w = tid >> 6, lane = tid & 63;
  int cl = lane & 31, hf = lane >> 5;
  __shared__ u16 Qs[128 * 64] __attribute__((aligned(16)));
  __shared__ u16 Ks[64 * 64]  __attribute__((aligned(16)));
  __shared__ u16 Vts[64 * 64] __attribute__((aligned(16)));
  __shared__ float padl[64];

#pragma unroll
  for (int it = 0; it < 4; it++) {
    int cid = it * 256 + tid; int r = cid >> 3, cc = cid & 7;
    uint4 d = *(const uint4*)(q + ((size_t)(b * TT + q0g + r)) * DD + n * HDIM + cc * 8);
    ((uint4*)Qs)[r * 8 + (cc ^ (r & 7))] = d;
  }
  __syncthreads();
  bf16x8 qf[4];
  int qrow = 32 * w + cl;
#pragma unroll
  for (int kc = 0; kc < 4; kc++)
    qf[kc] = ((const bf16x8*)Qs)[qrow * 8 + ((2 * kc + hf) ^ (cl & 7))];

  int tq = q0g + qrow;
  float prow = padc[b * TT + tq];
  bool prow_ok = (prow != 0.f);
  floatx16 o0 = ZERO16, o1 = ZERO16;
  float m_i = -INFINITY, l_i = 0.f;

  int jend = q0g + 128;
  for (int j0 = 0; j0 < jend; j0 += 64) {
#pragma unroll
    for (int it = 0; it < 2; it++) {
      int cid = it * 256 + tid; int r = cid >> 3, cc = cid & 7;
      uint4 dk = *(const uint4*)(k + ((size_t)(b * TT + j0 + r)) * DD + n * HDIM + cc * 8);
      ((uint4*)Ks)[r * 8 + (cc ^ (r & 7))] = dk;
      uint4 dv = *(const uint4*)(vT + ((size_t)(bn * HDIM + r)) * TT + j0 + cc * 8);
      ((uint4*)Vts)[r * 8 + (cc ^ (r & 7))] = dv;
    }
    if (tid < 64) padl[tid] = padc[b * TT + j0 + tid];
    __syncthreads();

    floatx16 s0 = ZERO16, s1 = ZERO16;
#pragma unroll
    for (int kc = 0; kc < 4; kc++) {
      bf16x8 ka0 = ((const bf16x8*)Ks)[cl * 8 + ((2 * kc + hf) ^ (cl & 7))];
      bf16x8 ka1 = ((const bf16x8*)Ks)[(32 + cl) * 8 + ((2 * kc + hf) ^ (cl & 7))];
      s0 = __builtin_amdgcn_mfma_f32_32x32x16_bf16(ka0, qf[kc], s0, 0, 0, 0);
      s1 = __builtin_amdgcn_mfma_f32_32x32x16_bf16(ka1, qf[kc], s1, 0, 0, 0);
    }

    float mloc = -INFINITY;
#pragma unroll
    for (int q2 = 0; q2 < 2; q2++) {
#pragma unroll
      for (int rg = 0; rg < 4; rg++) {
        float4 pv = *(const float4*)&padl[q2 * 32 + rg * 8 + 4 * hf];
        int kb = j0 + q2 * 32 + rg * 8 + 4 * hf;
#pragma unroll
        for (int j = 0; j < 4; j++) {
          int idx = rg * 4 + j;
          float sval = q2 ? s1[idx] : s0[idx];
          float pvj = (j == 0) ? pv.x : (j == 1) ? pv.y : (j == 2) ? pv.z : pv.w;
          bool ok = prow_ok && (kb + j <= tq) && (pvj != 0.f);
          sval = ok ? sval : -1e9f;
          if (q2) s1[idx] = sval; else s0[idx] = sval;
          mloc = fmaxf(mloc, sval);
        }
      }
    }
    float mtile = fmaxf(mloc, __shfl_xor(mloc, 32));
    float mnew = fmaxf(m_i, mtile);
    float alpha = __expf(m_i - mnew);
    m_i = mnew;
    float ls = 0.f;
#pragma unroll
    for (int i = 0; i < 16; i++) {
      float p0 = __expf(s0[i] - mnew); s0[i] = p0; ls += p0;
      float p1 = __expf(s1[i] - mnew); s1[i] = p1; ls += p1;
    }
    ls += __shfl_xor(ls, 32);
    l_i = l_i * alpha + ls;
    o0 *= alpha; o1 *= alpha;

    u32 pk[8][2];
#pragma unroll
    for (int q2 = 0; q2 < 2; q2++)
#pragma unroll
      for (int rg = 0; rg < 4; rg++) {
        int be = q2 * 4 + rg;
        float a0 = q2 ? s1[rg * 4 + 0] : s0[rg * 4 + 0];
        float a1 = q2 ? s1[rg * 4 + 1] : s0[rg * 4 + 1];
        float a2 = q2 ? s1[rg * 4 + 2] : s0[rg * 4 + 2];
        float a3 = q2 ? s1[rg * 4 + 3] : s0[rg * 4 + 3];
        pk[be][0] = (u32)f2b(a0) | ((u32)f2b(a1) << 16);
        pk[be][1] = (u32)f2b(a2) | ((u32)f2b(a3) << 16);
      }
    u32 pp[8][2];
#pragma unroll
    for (int be = 0; be < 8; be++) {
      pp[be][0] = (u32)__shfl_xor((int)pk[be][0], 32);
      pp[be][1] = (u32)__shfl_xor((int)pk[be][1], 32);
    }

#pragma unroll
    for (int kc = 0; kc < 4; kc++) {
      union { u32 wd[4]; bf16x8 v; } pb;
      if (hf == 0) {
        pb.wd[0] = pk[2 * kc][0];     pb.wd[1] = pk[2 * kc][1];
        pb.wd[2] = pp[2 * kc][0];     pb.wd[3] = pp[2 * kc][1];
      } else {
        pb.wd[0] = pp[2 * kc + 1][0]; pb.wd[1] = pp[2 * kc + 1][1];
        pb.wd[2] = pk[2 * kc + 1][0]; pb.wd[3] = pk[2 * kc + 1][1];
      }
      bf16x8 vf0 = ((const bf16x8*)Vts)[cl * 8 + ((2 * kc + hf) ^ (cl & 7))];
      bf16x8 vf1 = ((const bf16x8*)Vts)[(32 + cl) * 8 + ((2 * kc + hf) ^ (cl & 7))];
      o0 = __builtin_amdgcn_mfma_f32_32x32x16_bf16(vf0, pb.v, o0, 0, 0, 0);
      o1 = __builtin_amdgcn_mfma_f32_32x32x16_bf16(vf1, pb.v, o1, 0, 0, 0);
    }
    __syncthreads();
  }

  float rl = 1.f / l_i;
#pragma unroll
  for (int hq = 0; hq < 2; hq++)
#pragma unroll
    for (int rg = 0; rg < 4; rg++) {
      ushort4 st;
      st.x = f2b((hq ? o1[rg * 4 + 0] : o0[rg * 4 + 0]) * rl);
      st.y = f2b((hq ? o1[rg * 4 + 1] : o0[rg * 4 + 1]) * rl);
      st.z = f2b((hq ? o1[rg * 4 + 2] : o0[rg * 4 + 2]) * rl);
      st.w = f2b((hq ? o1[rg * 4 + 3] : o0[rg * 4 + 3]) * rl);
      int col = n * HDIM + hq * 32 + rg * 8 + 4 * hf;
      *(ushort4*)(ao + ((size_t)(b * TT + tq)) * DD + col) = st;
    }
}

extern "C" void kernel_launch(void* const* d_in, const int* in_sizes, int n_in,
                              void* d_out, int out_size, void* d_ws, size_t ws_size,
                              hipStream_t stream) {
  const float* x   = (const float*)d_in[0];
  const float* pad = (const float*)d_in[1];
  const float* rs  = (const float*)d_in[2];
  const float* pds = (const float*)d_in[3];
  const float* wq  = (const float*)d_in[4];
  const float* bq  = (const float*)d_in[5];
  const float* wk  = (const float*)d_in[6];
  const float* bk  = (const float*)d_in[7];
  const float* wv_ = (const float*)d_in[8];
  const float* bv  = (const float*)d_in[9];
  const float* wo  = (const float*)d_in[10];
  const float* bo  = (const float*)d_in[11];
  const float* lg  = (const float*)d_in[12];
  const float* lb  = (const float*)d_in[13];
  const float* w1  = (const float*)d_in[14];
  const float* b1  = (const float*)d_in[15];
  const float* w2  = (const float*)d_in[16];
  const float* b2  = (const float*)d_in[17];
  float* out = (float*)d_out;   // fp32 output

  const size_t MB = (size_t)1 << 20;
  int G;
  if      (ws_size >= 88 * MB) G = 8;
  else if (ws_size >= 56 * MB) G = 4;
  else if (ws_size >= 40 * MB) G = 2;
  else                         G = 1;

  char* w = (char*)d_ws;
  u16* wqkvT = (u16*)(w);           // [3072][1024] bf16 = wqT|wkT|wvT contiguous
  u16* woT   = (u16*)(w + 6 * MB);  // [1024][1024]
  u16* w1T   = (u16*)(w + 8 * MB);  // [4096][1024]
  u16* w2T   = (u16*)(w + 16 * MB); // [1024][4096]
  char* act = w + 24 * MB;
  const size_t SA = (size_t)2 * G * MB;   // one region: G*1024 rows x 1024 bf16
  u16*   regA = (u16*)act;             // xn -> vT -> hn
  u16*   qB   = (u16*)(act + SA);      // q  (qB,kC,vD contiguous for fused QKV)
  u16*   kC   = (u16*)(act + 2 * SA);  // k
  u16*   vD   = (u16*)(act + 3 * SA);  // v -> ao -> h1 panel
  float* att  = (float*)(act + SA);    // fp32 residual stream, spans qB+kC
  u16*   vTr  = regA;
  u16*   ao   = vD;
  u16*   hn   = regA;
  u16*   h1p  = vD;

  // small scratch in the tail of d_out (rewritten by final FFN2 afterwards)
  float* bqkv  = out + (size_t)out_size - 8192;
  float* qsall = bqkv + 3072;

  transpose_conv<<<dim3(32, 32),  256, 0, stream>>>(wq,  wqkvT,              DD, DD);
  transpose_conv<<<dim3(32, 32),  256, 0, stream>>>(wk,  wqkvT + 1024 * 1024, DD, DD);
  transpose_conv<<<dim3(32, 32),  256, 0, stream>>>(wv_, wqkvT + 2048 * 1024, DD, DD);
  conv_bf16<<<1024, 256, 0, stream>>>(wo, woT);
  transpose_conv<<<dim3(128, 32), 256, 0, stream>>>(w1, w1T, DD, FF);
  transpose_conv<<<dim3(32, 128), 256, 0, stream>>>(w2, w2T, FF, DD);
  prep_kernel<<<3, 1024, 0, stream>>>(bq, bk, bv, pds, bqkv, qsall);

  const int R = G * 1024;

  for (int c0 = 0; c0 < BB / G; c0++) {
    size_t rowoff = (size_t)c0 * R;
    const float* xc = x + rowoff * DD;

    rms_kernel<<<R, 256, 0, stream>>>(xc, rs, regA);

    // fused QKV: N=3072 -> grid (24, R/128); out regions qB/kC/vD via regstride
    mfma_gemm<u16><<<dim3(24, R / 128), 256, 0, stream>>>(
        regA, wqkvT, bqkv, nullptr, qsall, qB,
        DD, DD, DD, 0, (size_t)R * 1024);

    vtrans_kernel<<<dim3(TT / 64, G * NHEAD), 256, 0, stream>>>(vD, vTr);

    attn_mfma<<<dim3(TT / 128, G * NHEAD), 256, 0, stream>>>(
        qB, kC, vTr, pad + rowoff, ao);

    // o-proj: att = ao @ wo^T + bo + x
    mfma_gemm<float><<<dim3(8, R / 128), 256, 0, stream>>>(
        ao, woT, bo, xc, nullptr, att, DD, DD, DD, 0, 0);

    ln_kernel<<<R, 256, 0, stream>>>(att, lg, lb, hn);

    // FFN in 4 column panels of F: full-R grids (8, R/128)
    for (int f = 0; f < 4; f++) {
      mfma_gemm<u16><<<dim3(8, R / 128), 256, 0, stream>>>(
          hn, w1T + (size_t)f * 1024 * 1024, b1 + f * 1024, nullptr, nullptr,
          h1p, DD, DD, DD, 1, 0);
      if (f < 3)
        mfma_gemm<float><<<dim3(8, R / 128), 256, 0, stream>>>(
            h1p, w2T + f * 1024, (f == 0) ? b2 : nullptr, att, nullptr,
            att, DD, FF, DD, 0, 0);
      else
        mfma_gemm<float><<<dim3(8, R / 128), 256, 0, stream>>>(
            h1p, w2T + f * 1024, nullptr, att, nullptr,
            out + rowoff * DD, DD, FF, DD, 0, 0);
    }
  }
}